// Round 3
// baseline (1204.859 us; speedup 1.0000x reference)
//
#include <hip/hip_runtime.h>
#include <hip/hip_bf16.h>

// ---------------- dtype-robust load helpers ----------------
__device__ __forceinline__ float getf(const void* p, size_t i, int isf32){
  return isf32 ? ((const float*)p)[i]
               : __bfloat162float(((const __hip_bfloat16*)p)[i]);
}
__device__ __forceinline__ int getedge(const void* p, long long idx, int is64, int n){
  long long v = is64 ? ((const long long*)p)[idx] : (long long)((const int*)p)[idx];
  v = v < 0 ? 0 : (v >= n ? (long long)(n - 1) : v);
  return (int)v;
}

__device__ __forceinline__ float bfly_sum(float v){
#pragma unroll
  for (int m = 32; m > 0; m >>= 1) v += __shfl_xor(v, m, 64);
  return v;
}
__device__ __forceinline__ float bfly_max(float v){
#pragma unroll
  for (int m = 32; m > 0; m >>= 1) v = fmaxf(v, __shfl_xor(v, m, 64));
  return v;
}

// ---------------- runtime dtype detection ----------------
__global__ __launch_bounds__(256) void detect_kernel(const void* x, const void* ei,
                                                     int* flags){
  __shared__ int cnt_sane, cnt_odd;
  int t = threadIdx.x;
  if (t == 0){ cnt_sane = 0; cnt_odd = 0; }
  __syncthreads();
  int sane = 0;
  for (int i = t; i < 4096; i += 256){
    float v = __bfloat162float(((const __hip_bfloat16*)x)[i]);
    if (fabsf(v) < 16.f) sane++;          // true-bf16 data: ~100%; fp32-bytes: ~75%
  }
  atomicAdd(&cnt_sane, sane);
  int odd = 0;
  for (int i = t; i < 512; i += 256){
    if (((const int*)ei)[2 * i + 1] != 0) odd++;  // int64 data: high halves all 0
  }
  atomicAdd(&cnt_odd, odd);
  __syncthreads();
  if (t == 0){
    flags[0] = (cnt_sane < 3900) ? 1 : 0;  // 1 => float inputs are fp32
    flags[1] = (cnt_odd == 0) ? 1 : 0;     // 1 => edge_index is int64
  }
}

// ---------------- graph bucketing ----------------
__global__ __launch_bounds__(256) void count_kernel(const void* __restrict__ ei, long long E,
                                                    int n, const int* __restrict__ flags,
                                                    int* __restrict__ cnt){
  int i = blockIdx.x * blockDim.x + threadIdx.x;
  if (i < E){
    int d = getedge(ei, E + i, flags[1], n);
    atomicAdd(&cnt[d], 1);
  }
}

__global__ __launch_bounds__(1024) void scan_kernel(const int* __restrict__ cnt, int* __restrict__ off,
                                                    int* __restrict__ pos, int n){
  __shared__ int wsum[16];
  __shared__ int carry_s;
  int tid = threadIdx.x, lane = tid & 63, wv = tid >> 6;
  if (tid == 0) carry_s = 0;
  __syncthreads();
  for (int base = 0; base < n; base += 1024){
    int i = base + tid;
    int v = (i < n) ? cnt[i] : 0;
    int s = v;
#pragma unroll
    for (int o = 1; o < 64; o <<= 1){ int t = __shfl_up(s, o, 64); if (lane >= o) s += t; }
    if (lane == 63) wsum[wv] = s;
    __syncthreads();
    int wo = 0;
    for (int w = 0; w < wv; w++) wo += wsum[w];
    int carry = carry_s;
    int excl = carry + wo + s - v;
    if (i < n){ off[i] = excl; pos[i] = excl; }
    __syncthreads();
    if (tid == 0){
      int tot = 0;
      for (int w = 0; w < 16; w++) tot += wsum[w];
      carry_s = carry + tot;
    }
    __syncthreads();
  }
  if (tid == 0) off[n] = carry_s;
}

__global__ __launch_bounds__(256) void fill_kernel(const void* __restrict__ ei, long long E,
                                                   int n, const int* __restrict__ flags,
                                                   int* __restrict__ pos, int* __restrict__ bsrc){
  int i = blockIdx.x * blockDim.x + threadIdx.x;
  if (i < E){
    int d = getedge(ei, E + i, flags[1], n);
    int s = getedge(ei, i, flags[1], n);
    int p = atomicAdd(&pos[d], 1);
    bsrc[p] = s;
  }
}

// ---------------- fp32 GEMM: A [M,K] (AMODE 0: fp32 buf, 1: detected input), B [K,N] detected ----------------
template<int AMODE, bool RELU, bool BIAS>
__global__ __launch_bounds__(256) void gemm_kernel(const void* __restrict__ A,
    const void* __restrict__ B, const void* __restrict__ bias, const int* __restrict__ flags,
    float* __restrict__ C, int M, int N, int K)
{
  constexpr int BM = 64, BN = 64, BK = 16;
  __shared__ float As[BK][BM + 4];
  __shared__ float Bs[BK][BN + 4];
  int f0 = flags[0];
  int tid = threadIdx.x;
  int bm = blockIdx.x * BM;
  int bn = blockIdx.y * BN;
  int rowb = (tid >> 4) << 2;
  int colb = (tid & 15) << 2;
  float acc[4][4] = {};
  for (int k0 = 0; k0 < K; k0 += BK){
    {
      int m  = tid >> 2;
      int kk = (tid & 3) << 2;
      int gr = bm + m;
      if (gr < M){
        size_t base = (size_t)gr * K + k0 + kk;
        if (AMODE == 0){
          const float* ap = (const float*)A + base;
          As[kk+0][m] = ap[0]; As[kk+1][m] = ap[1]; As[kk+2][m] = ap[2]; As[kk+3][m] = ap[3];
        } else {
          As[kk+0][m] = getf(A, base+0, f0); As[kk+1][m] = getf(A, base+1, f0);
          As[kk+2][m] = getf(A, base+2, f0); As[kk+3][m] = getf(A, base+3, f0);
        }
      } else {
        As[kk+0][m] = 0.f; As[kk+1][m] = 0.f; As[kk+2][m] = 0.f; As[kk+3][m] = 0.f;
      }
    }
#pragma unroll
    for (int r = 0; r < 4; r++){
      int e = tid + r * 256;
      int kb = e >> 6, c = e & 63;
      Bs[kb][c] = getf(B, (size_t)(k0 + kb) * N + bn + c, f0);
    }
    __syncthreads();
#pragma unroll
    for (int kk = 0; kk < BK; kk++){
      float a0 = As[kk][rowb+0], a1 = As[kk][rowb+1], a2 = As[kk][rowb+2], a3 = As[kk][rowb+3];
      float b0 = Bs[kk][colb+0], b1 = Bs[kk][colb+1], b2 = Bs[kk][colb+2], b3 = Bs[kk][colb+3];
      acc[0][0] += a0*b0; acc[0][1] += a0*b1; acc[0][2] += a0*b2; acc[0][3] += a0*b3;
      acc[1][0] += a1*b0; acc[1][1] += a1*b1; acc[1][2] += a1*b2; acc[1][3] += a1*b3;
      acc[2][0] += a2*b0; acc[2][1] += a2*b1; acc[2][2] += a2*b2; acc[2][3] += a2*b3;
      acc[3][0] += a3*b0; acc[3][1] += a3*b1; acc[3][2] += a3*b2; acc[3][3] += a3*b3;
    }
    __syncthreads();
  }
#pragma unroll
  for (int i = 0; i < 4; i++){
    int gr = bm + rowb + i;
    if (gr < M){
#pragma unroll
      for (int j = 0; j < 4; j++){
        int gc = bn + colb + j;
        float v = acc[i][j];
        if (BIAS) v += getf(bias, gc, f0);
        if (RELU) v = fmaxf(v, 0.f);
        C[(size_t)gr * N + gc] = v;
      }
    }
  }
}

// ---------------- attention logits ----------------
__global__ __launch_bounds__(256) void al0_kernel(const float* __restrict__ xw,
    const void* __restrict__ a_s, const void* __restrict__ a_d, const int* __restrict__ flags,
    float* __restrict__ als, float* __restrict__ ald, int n)
{
  int f0 = flags[0];
  int i = blockIdx.x, t = threadIdx.x;
  int h = t >> 6, lane = t & 63;
  float v = xw[(size_t)i * 256 + t];
  float ps = v * getf(a_s, t, f0);
  float pd = v * getf(a_d, t, f0);
  ps = bfly_sum(ps); pd = bfly_sum(pd);
  if (lane == 0){ als[(size_t)i * 4 + h] = ps; ald[(size_t)i * 4 + h] = pd; }
}

__global__ __launch_bounds__(128) void al1_kernel(const float* __restrict__ xw,
    const void* __restrict__ a_s, const void* __restrict__ a_d, const int* __restrict__ flags,
    float* __restrict__ als, float* __restrict__ ald, int n)
{
  __shared__ float rs[2], rd[2];
  int f0 = flags[0];
  int i = blockIdx.x, t = threadIdx.x;
  int wv = t >> 6, lane = t & 63;
  float v = xw[(size_t)i * 128 + t];
  float ps = v * getf(a_s, t, f0);
  float pd = v * getf(a_d, t, f0);
  ps = bfly_sum(ps); pd = bfly_sum(pd);
  if (lane == 0){ rs[wv] = ps; rd[wv] = pd; }
  __syncthreads();
  if (t == 0){ als[i] = rs[0] + rs[1]; ald[i] = rd[0] + rd[1]; }
}

// ---------------- GAT aggregation + bias + LayerNorm (+residual+relu) ----------------
template<int H, int C, bool RES>
__global__ __launch_bounds__(H*C) void agg_kernel(
    const float* __restrict__ xw, const float* __restrict__ als, const float* __restrict__ ald,
    const int* __restrict__ bsrc, const int* __restrict__ off,
    const void* __restrict__ bias, const void* __restrict__ gamma,
    const void* __restrict__ beta, const int* __restrict__ flags,
    const float* __restrict__ res, float* __restrict__ outp, int n)
{
  constexpr int T = H * C;
  constexpr int NW = T / 64;
  int f0 = flags[0];
  int i = blockIdx.x;
  int t = threadIdx.x, wv = t >> 6, lane = t & 63;
  int h = t / C;
  int e0 = off[i];
  int deg = off[i + 1] - e0;
  int tot = deg + 1;                 // + self loop

  __shared__ float s_w[H][64];
  __shared__ int   s_src[64];
  __shared__ float s_red[NW];

  float m = -1e30f, linv = 0.f, ad_i = 0.f;
  if (wv < H){
    ad_i = ald[(size_t)i * H + wv];
    for (int j = lane; j < tot; j += 64){
      int s = (j < deg) ? bsrc[e0 + j] : i;
      float e = als[(size_t)s * H + wv] + ad_i;
      e = (e > 0.f) ? e : 0.2f * e;
      m = fmaxf(m, e);
    }
    m = bfly_max(m);
    float l = 0.f;
    for (int j = lane; j < tot; j += 64){
      int s = (j < deg) ? bsrc[e0 + j] : i;
      float e = als[(size_t)s * H + wv] + ad_i;
      e = (e > 0.f) ? e : 0.2f * e;
      l += __expf(e - m);
    }
    l = bfly_sum(l);
    linv = 1.f / l;
  }
  __syncthreads();

  float macc = 0.f;
  for (int cb = 0; cb < tot; cb += 64){
    int cnt = min(64, tot - cb);
    if (wv == 0 && lane < cnt){
      int j = cb + lane;
      s_src[lane] = (j < deg) ? bsrc[e0 + j] : i;
    }
    __syncthreads();
    if (wv < H && lane < cnt){
      int s = s_src[lane];
      float e = als[(size_t)s * H + wv] + ad_i;
      e = (e > 0.f) ? e : 0.2f * e;
      s_w[wv][lane] = __expf(e - m) * linv;
    }
    __syncthreads();
    for (int jj = 0; jj < cnt; jj++){
      macc += s_w[h][jj] * xw[(size_t)s_src[jj] * T + t];
    }
    __syncthreads();
  }

  float v = macc + getf(bias, t, f0);
  float s1 = bfly_sum(v);
  if (lane == 0) s_red[wv] = s1;
  __syncthreads();
  float mu = 0.f;
#pragma unroll
  for (int w = 0; w < NW; w++) mu += s_red[w];
  mu *= (1.f / T);
  __syncthreads();
  float d = v - mu;
  float s2 = bfly_sum(d * d);
  if (lane == 0) s_red[wv] = s2;
  __syncthreads();
  float var = 0.f;
#pragma unroll
  for (int w = 0; w < NW; w++) var += s_red[w];
  var *= (1.f / T);
  float y = d * rsqrtf(var + 1e-5f) * getf(gamma, t, f0) + getf(beta, t, f0);
  if constexpr (RES){
    y = y + res[(size_t)i * T + t];
    y = fmaxf(y, 0.f);
  }
  outp[(size_t)i * T + t] = y;
}

// ---------------- final: h2 @ Wo + bo, row-normalize, write fp32 ----------------
__global__ __launch_bounds__(128) void out_kernel(const float* __restrict__ h2,
    const void* __restrict__ Wo, const void* __restrict__ bo, const int* __restrict__ flags,
    float* __restrict__ outp, int n)
{
  __shared__ float sW[128 * 128];
  __shared__ float srow[128];
  __shared__ float sred[2];
  int f0 = flags[0];
  int t = threadIdx.x, wv = t >> 6, lane = t & 63;
  for (int e = t; e < 128 * 128; e += 128) sW[e] = getf(Wo, e, f0);
  float bj = getf(bo, t, f0);
  __syncthreads();
  for (int i = blockIdx.x; i < n; i += gridDim.x){
    srow[t] = h2[(size_t)i * 128 + t];
    __syncthreads();
    float acc = bj;
#pragma unroll 8
    for (int k = 0; k < 128; k++) acc += srow[k] * sW[k * 128 + t];
    float ss = bfly_sum(acc * acc);
    if (lane == 0) sred[wv] = ss;
    __syncthreads();
    float tot = sred[0] + sred[1];
    float inv = 1.f / fmaxf(sqrtf(tot), 1e-12f);
    outp[(size_t)i * 128 + t] = acc * inv;
    __syncthreads();
  }
}

// ---------------- launch ----------------
extern "C" void kernel_launch(void* const* d_in, const int* in_sizes, int n_in,
                              void* d_out, int out_size, void* d_ws, size_t ws_size,
                              hipStream_t stream)
{
  const void* x   = d_in[0];
  const void* ei  = d_in[1];
  const void* Wp  = d_in[2];
  const void* bp  = d_in[3];
  const void* W0  = d_in[4];
  const void* as0 = d_in[5];
  const void* ad0 = d_in[6];
  const void* b0  = d_in[7];
  const void* W1  = d_in[8];
  const void* as1 = d_in[9];
  const void* ad1 = d_in[10];
  const void* b1  = d_in[11];
  const void* g0  = d_in[12];
  const void* be0 = d_in[13];
  const void* g1  = d_in[14];
  const void* be1 = d_in[15];
  const void* Wo  = d_in[16];
  const void* bo  = d_in[17];
  float* outp = (float*)d_out;

  const int n = in_sizes[0] / 256;   // 50000
  const int E = in_sizes[1] / 2;     // 800000

  char* w = (char*)d_ws;
  size_t SZ = (size_t)n * 256 * sizeof(float);
  float* h_buf  = (float*)w;             // h -> h1 -> h2
  float* xw_buf = (float*)(w + SZ);      // xw0 -> xw1
  char* p = w + 2 * SZ;
  int* flags = (int*)p; p += 64;
  float* als0 = (float*)p; p += (size_t)n * 4 * sizeof(float);
  float* ald0 = (float*)p; p += (size_t)n * 4 * sizeof(float);
  float* als1 = (float*)p; p += (size_t)n * sizeof(float);
  float* ald1 = (float*)p; p += (size_t)n * sizeof(float);
  int* cnt  = (int*)p; p += (size_t)n * sizeof(int);
  int* offb = (int*)p; p += (size_t)(n + 1) * sizeof(int) + 4;
  int* pos  = (int*)p; p += (size_t)n * sizeof(int);
  int* bsrc = (int*)p; p += (size_t)E * sizeof(int);

  detect_kernel<<<1, 256, 0, stream>>>(x, ei, flags);

  hipMemsetAsync(cnt, 0, (size_t)n * sizeof(int), stream);
  count_kernel<<<(E + 255) / 256, 256, 0, stream>>>(ei, E, n, flags, cnt);
  scan_kernel<<<1, 1024, 0, stream>>>(cnt, offb, pos, n);
  fill_kernel<<<(E + 255) / 256, 256, 0, stream>>>(ei, E, n, flags, pos, bsrc);

  int mblk = (n + 63) / 64;
  // h = relu(x @ Wp + bp)
  gemm_kernel<1, true, true><<<dim3(mblk, 4), 256, 0, stream>>>(x, Wp, bp, flags, h_buf, n, 256, 256);
  // xw0 = h @ W0
  gemm_kernel<0, false, false><<<dim3(mblk, 4), 256, 0, stream>>>(h_buf, W0, nullptr, flags, xw_buf, n, 256, 256);
  al0_kernel<<<n, 256, 0, stream>>>(xw_buf, as0, ad0, flags, als0, ald0, n);
  // layer-0 aggregate + b0 + LN + residual + relu -> h1 (in-place rows of h_buf)
  agg_kernel<4, 64, true><<<n, 256, 0, stream>>>(xw_buf, als0, ald0, bsrc, offb, b0, g0, be0, flags, h_buf, h_buf, n);
  // xw1 = h1 @ W1
  gemm_kernel<0, false, false><<<dim3(mblk, 2), 256, 0, stream>>>(h_buf, W1, nullptr, flags, xw_buf, n, 128, 256);
  al1_kernel<<<n, 128, 0, stream>>>(xw_buf, as1, ad1, flags, als1, ald1, n);
  // layer-1 aggregate + b1 + LN -> h2 (reuse h_buf as n x 128)
  agg_kernel<1, 128, false><<<n, 128, 0, stream>>>(xw_buf, als1, ald1, bsrc, offb, b1, g1, be1, flags, nullptr, h_buf, n);
  // out = normalize(h2 @ Wo + bo)
  out_kernel<<<2048, 128, 0, stream>>>(h_buf, Wo, bo, flags, outp, n);
}

// Round 4
// 938.668 us; speedup vs baseline: 1.2836x; 1.2836x over previous
//
#include <hip/hip_runtime.h>
#include <hip/hip_bf16.h>

typedef __bf16 bf16x8 __attribute__((ext_vector_type(8)));
typedef __bf16 bf16x4 __attribute__((ext_vector_type(4)));
typedef float f32x4 __attribute__((ext_vector_type(4)));

// ---------------- dtype-robust load helpers ----------------
__device__ __forceinline__ float getf(const void* p, size_t i, int isf32){
  return isf32 ? ((const float*)p)[i]
               : __bfloat162float(((const __hip_bfloat16*)p)[i]);
}
__device__ __forceinline__ int getedge(const void* p, long long idx, int is64, int n){
  long long v = is64 ? ((const long long*)p)[idx] : (long long)((const int*)p)[idx];
  v = v < 0 ? 0 : (v >= n ? (long long)(n - 1) : v);
  return (int)v;
}

__device__ __forceinline__ float bfly_sum(float v){
#pragma unroll
  for (int m = 32; m > 0; m >>= 1) v += __shfl_xor(v, m, 64);
  return v;
}
__device__ __forceinline__ float bfly_max(float v){
#pragma unroll
  for (int m = 32; m > 0; m >>= 1) v = fmaxf(v, __shfl_xor(v, m, 64));
  return v;
}

// ---------------- runtime dtype detection ----------------
__global__ __launch_bounds__(256) void detect_kernel(const void* x, const void* ei,
                                                     int* flags){
  __shared__ int cnt_sane, cnt_odd;
  int t = threadIdx.x;
  if (t == 0){ cnt_sane = 0; cnt_odd = 0; }
  __syncthreads();
  int sane = 0;
  for (int i = t; i < 4096; i += 256){
    float v = __bfloat162float(((const __hip_bfloat16*)x)[i]);
    if (fabsf(v) < 16.f) sane++;
  }
  atomicAdd(&cnt_sane, sane);
  int odd = 0;
  for (int i = t; i < 512; i += 256){
    if (((const int*)ei)[2 * i + 1] != 0) odd++;
  }
  atomicAdd(&cnt_odd, odd);
  __syncthreads();
  if (t == 0){
    flags[0] = (cnt_sane < 3900) ? 1 : 0;  // 1 => float inputs are fp32
    flags[1] = (cnt_odd == 0) ? 1 : 0;     // 1 => edge_index is int64
  }
}

// ---------------- graph bucketing ----------------
__global__ __launch_bounds__(256) void count_kernel(const void* __restrict__ ei, long long E,
                                                    int n, const int* __restrict__ flags,
                                                    int* __restrict__ cnt){
  int i = blockIdx.x * blockDim.x + threadIdx.x;
  if (i < E){
    int d = getedge(ei, E + i, flags[1], n);
    atomicAdd(&cnt[d], 1);
  }
}

__global__ __launch_bounds__(1024) void scan_kernel(const int* __restrict__ cnt, int* __restrict__ off,
                                                    int* __restrict__ pos, int n){
  __shared__ int wsum[16];
  __shared__ int carry_s;
  int tid = threadIdx.x, lane = tid & 63, wv = tid >> 6;
  if (tid == 0) carry_s = 0;
  __syncthreads();
  for (int base = 0; base < n; base += 1024){
    int i = base + tid;
    int v = (i < n) ? cnt[i] : 0;
    int s = v;
#pragma unroll
    for (int o = 1; o < 64; o <<= 1){ int t = __shfl_up(s, o, 64); if (lane >= o) s += t; }
    if (lane == 63) wsum[wv] = s;
    __syncthreads();
    int wo = 0;
    for (int w = 0; w < wv; w++) wo += wsum[w];
    int carry = carry_s;
    int excl = carry + wo + s - v;
    if (i < n){ off[i] = excl; pos[i] = excl; }
    __syncthreads();
    if (tid == 0){
      int tot = 0;
      for (int w = 0; w < 16; w++) tot += wsum[w];
      carry_s = carry + tot;
    }
    __syncthreads();
  }
  if (tid == 0) off[n] = carry_s;
}

__global__ __launch_bounds__(256) void fill_kernel(const void* __restrict__ ei, long long E,
                                                   int n, const int* __restrict__ flags,
                                                   int* __restrict__ pos, int* __restrict__ bsrc){
  int i = blockIdx.x * blockDim.x + threadIdx.x;
  if (i < E){
    int d = getedge(ei, E + i, flags[1], n);
    int s = getedge(ei, i, flags[1], n);
    int p = atomicAdd(&pos[d], 1);
    bsrc[p] = s;
  }
}

// ---------------- bf16 MFMA GEMM: C[M,N] = A[M,K] @ B[K,N] (+bias, relu) ----------------
// Block: 256 thr = 4 waves; tile 128(M) x 64(N); A converted fp32->bf16 into LDS,
// B staged full-K per block. fp32 accumulate via v_mfma_f32_16x16x32_bf16.
// LDS strides: A 40 elts (80B) / B 264 elts (528B) -> fragment ds_read_b128 2-way banked (free).
template<int AMODE, bool RELU, bool BIAS>
__global__ __launch_bounds__(256) void mfma_gemm_kernel(const void* __restrict__ A,
    const void* __restrict__ B, const void* __restrict__ bias, const int* __restrict__ flags,
    float* __restrict__ C, int M, int N, int K)
{
  __shared__ __align__(16) __bf16 sA[128 * 40];
  __shared__ __align__(16) __bf16 sB[64 * 264];
  int f0 = flags[0];
  const bool af32 = (AMODE == 0) || (f0 != 0);
  int t = threadIdx.x;
  int bm = blockIdx.x * 128, bn = blockIdx.y * 64;

  // stage B^T: sB[n][k], n in [0,64), k in [0,K)
  for (int e = t; e < 64 * K; e += 256){
    int nn = e & 63, kk = e >> 6;
    sB[nn * 264 + kk] = (__bf16)getf(B, (size_t)kk * N + bn + nn, f0);
  }

  int wave = t >> 6, lane = t & 63, q = lane >> 4, mi = lane & 15;
  int m0w = (wave & 1) * 64, n0w = (wave >> 1) * 32;
  int k4 = (t & 7) * 4;          // k offset within 32-wide A tile
  int r0 = t >> 3;               // 0..31 row group
  f32x4 acc[4][2] = {};
  __syncthreads();

  for (int k0 = 0; k0 < K; k0 += 32){
    // stage A tile 128x32 (fp32 -> bf16)
#pragma unroll
    for (int it = 0; it < 4; it++){
      int row = r0 + it * 32;
      int gr = bm + row;
      float vx = 0.f, vy = 0.f, vz = 0.f, vw = 0.f;
      if (gr < M){
        size_t g = (size_t)gr * K + k0 + k4;
        if (af32){
          const f32x4 v = *(const f32x4*)((const float*)A + g);
          vx = v.x; vy = v.y; vz = v.z; vw = v.w;
        } else {
          const __hip_bfloat16* bp8 = (const __hip_bfloat16*)A + g;
          vx = __bfloat162float(bp8[0]); vy = __bfloat162float(bp8[1]);
          vz = __bfloat162float(bp8[2]); vw = __bfloat162float(bp8[3]);
        }
      }
      bf16x4 pk;
      pk.x = (__bf16)vx; pk.y = (__bf16)vy; pk.z = (__bf16)vz; pk.w = (__bf16)vw;
      *(bf16x4*)&sA[row * 40 + k4] = pk;
    }
    __syncthreads();
    bf16x8 bfr0 = *(const bf16x8*)&sB[(n0w + 0 * 16 + mi) * 264 + k0 + q * 8];
    bf16x8 bfr1 = *(const bf16x8*)&sB[(n0w + 1 * 16 + mi) * 264 + k0 + q * 8];
#pragma unroll
    for (int mt = 0; mt < 4; mt++){
      bf16x8 afr = *(const bf16x8*)&sA[(m0w + mt * 16 + mi) * 40 + q * 8];
      acc[mt][0] = __builtin_amdgcn_mfma_f32_16x16x32_bf16(afr, bfr0, acc[mt][0], 0, 0, 0);
      acc[mt][1] = __builtin_amdgcn_mfma_f32_16x16x32_bf16(afr, bfr1, acc[mt][1], 0, 0, 0);
    }
    __syncthreads();
  }

  // epilogue: C/D layout col = lane&15, row = (lane>>4)*4 + reg
#pragma unroll
  for (int mt = 0; mt < 4; mt++){
    int rowb = bm + m0w + mt * 16 + q * 4;
#pragma unroll
    for (int r = 0; r < 4; r++){
      int row = rowb + r;
      if (row < M){
#pragma unroll
        for (int nt = 0; nt < 2; nt++){
          int col = bn + n0w + nt * 16 + mi;
          float v = acc[mt][nt][r];
          if (BIAS) v += getf(bias, col, f0);
          if (RELU) v = fmaxf(v, 0.f);
          C[(size_t)row * N + col] = v;
        }
      }
    }
  }
}

// ---------------- attention logits ----------------
__global__ __launch_bounds__(256) void al0_kernel(const float* __restrict__ xw,
    const void* __restrict__ a_s, const void* __restrict__ a_d, const int* __restrict__ flags,
    float* __restrict__ als, float* __restrict__ ald, int n)
{
  int f0 = flags[0];
  int i = blockIdx.x, t = threadIdx.x;
  int h = t >> 6, lane = t & 63;
  float v = xw[(size_t)i * 256 + t];
  float ps = v * getf(a_s, t, f0);
  float pd = v * getf(a_d, t, f0);
  ps = bfly_sum(ps); pd = bfly_sum(pd);
  if (lane == 0){ als[(size_t)i * 4 + h] = ps; ald[(size_t)i * 4 + h] = pd; }
}

__global__ __launch_bounds__(128) void al1_kernel(const float* __restrict__ xw,
    const void* __restrict__ a_s, const void* __restrict__ a_d, const int* __restrict__ flags,
    float* __restrict__ als, float* __restrict__ ald, int n)
{
  __shared__ float rs[2], rd[2];
  int f0 = flags[0];
  int i = blockIdx.x, t = threadIdx.x;
  int wv = t >> 6, lane = t & 63;
  float v = xw[(size_t)i * 128 + t];
  float ps = v * getf(a_s, t, f0);
  float pd = v * getf(a_d, t, f0);
  ps = bfly_sum(ps); pd = bfly_sum(pd);
  if (lane == 0){ rs[wv] = ps; rd[wv] = pd; }
  __syncthreads();
  if (t == 0){ als[i] = rs[0] + rs[1]; ald[i] = rd[0] + rd[1]; }
}

// ---------------- GAT aggregation + bias + LayerNorm (+residual+relu) ----------------
template<int H, int C, bool RES>
__global__ __launch_bounds__(H*C) void agg_kernel(
    const float* __restrict__ xw, const float* __restrict__ als, const float* __restrict__ ald,
    const int* __restrict__ bsrc, const int* __restrict__ off,
    const void* __restrict__ bias, const void* __restrict__ gamma,
    const void* __restrict__ beta, const int* __restrict__ flags,
    const float* __restrict__ res, float* __restrict__ outp, int n)
{
  constexpr int T = H * C;
  constexpr int NW = T / 64;
  int f0 = flags[0];
  int i = blockIdx.x;
  int t = threadIdx.x, wv = t >> 6, lane = t & 63;
  int h = t / C;
  int e0 = off[i];
  int deg = off[i + 1] - e0;
  int tot = deg + 1;                 // + self loop

  __shared__ float s_w[H][64];
  __shared__ int   s_src[64];
  __shared__ float s_red[NW];

  float m = -1e30f, linv = 0.f, ad_i = 0.f;
  if (wv < H){
    ad_i = ald[(size_t)i * H + wv];
    for (int j = lane; j < tot; j += 64){
      int s = (j < deg) ? bsrc[e0 + j] : i;
      float e = als[(size_t)s * H + wv] + ad_i;
      e = (e > 0.f) ? e : 0.2f * e;
      m = fmaxf(m, e);
    }
    m = bfly_max(m);
    float l = 0.f;
    for (int j = lane; j < tot; j += 64){
      int s = (j < deg) ? bsrc[e0 + j] : i;
      float e = als[(size_t)s * H + wv] + ad_i;
      e = (e > 0.f) ? e : 0.2f * e;
      l += __expf(e - m);
    }
    l = bfly_sum(l);
    linv = 1.f / l;
  }
  __syncthreads();

  float macc = 0.f;
  for (int cb = 0; cb < tot; cb += 64){
    int cnt = min(64, tot - cb);
    if (wv == 0 && lane < cnt){
      int j = cb + lane;
      s_src[lane] = (j < deg) ? bsrc[e0 + j] : i;
    }
    __syncthreads();
    if (wv < H && lane < cnt){
      int s = s_src[lane];
      float e = als[(size_t)s * H + wv] + ad_i;
      e = (e > 0.f) ? e : 0.2f * e;
      s_w[wv][lane] = __expf(e - m) * linv;
    }
    __syncthreads();
    for (int jj = 0; jj < cnt; jj++){
      macc += s_w[h][jj] * xw[(size_t)s_src[jj] * T + t];
    }
    __syncthreads();
  }

  float v = macc + getf(bias, t, f0);
  float s1 = bfly_sum(v);
  if (lane == 0) s_red[wv] = s1;
  __syncthreads();
  float mu = 0.f;
#pragma unroll
  for (int w = 0; w < NW; w++) mu += s_red[w];
  mu *= (1.f / T);
  __syncthreads();
  float d = v - mu;
  float s2 = bfly_sum(d * d);
  if (lane == 0) s_red[wv] = s2;
  __syncthreads();
  float var = 0.f;
#pragma unroll
  for (int w = 0; w < NW; w++) var += s_red[w];
  var *= (1.f / T);
  float y = d * rsqrtf(var + 1e-5f) * getf(gamma, t, f0) + getf(beta, t, f0);
  if constexpr (RES){
    y = y + res[(size_t)i * T + t];
    y = fmaxf(y, 0.f);
  }
  outp[(size_t)i * T + t] = y;
}

// ---------------- row L2-normalize: out[i,:] = in[i,:] / max(||in[i,:]||, 1e-12) ----------------
__global__ __launch_bounds__(128) void norm_kernel(const float* __restrict__ in,
                                                   float* __restrict__ outp, int n)
{
  __shared__ float sred[2];
  int i = blockIdx.x, t = threadIdx.x, wv = t >> 6, lane = t & 63;
  float v = in[(size_t)i * 128 + t];
  float ss = bfly_sum(v * v);
  if (lane == 0) sred[wv] = ss;
  __syncthreads();
  float inv = 1.f / fmaxf(sqrtf(sred[0] + sred[1]), 1e-12f);
  outp[(size_t)i * 128 + t] = v * inv;
}

// ---------------- launch ----------------
extern "C" void kernel_launch(void* const* d_in, const int* in_sizes, int n_in,
                              void* d_out, int out_size, void* d_ws, size_t ws_size,
                              hipStream_t stream)
{
  const void* x   = d_in[0];
  const void* ei  = d_in[1];
  const void* Wp  = d_in[2];
  const void* bp  = d_in[3];
  const void* W0  = d_in[4];
  const void* as0 = d_in[5];
  const void* ad0 = d_in[6];
  const void* b0  = d_in[7];
  const void* W1  = d_in[8];
  const void* as1 = d_in[9];
  const void* ad1 = d_in[10];
  const void* b1  = d_in[11];
  const void* g0  = d_in[12];
  const void* be0 = d_in[13];
  const void* g1  = d_in[14];
  const void* be1 = d_in[15];
  const void* Wo  = d_in[16];
  const void* bo  = d_in[17];
  float* outp = (float*)d_out;

  const int n = in_sizes[0] / 256;   // 50000
  const int E = in_sizes[1] / 2;     // 800000

  char* w = (char*)d_ws;
  size_t SZ = (size_t)n * 256 * sizeof(float);
  float* h_buf  = (float*)w;             // h -> h1 -> h2
  float* xw_buf = (float*)(w + SZ);      // xw0 -> xw1 -> pre-norm out
  char* p = w + 2 * SZ;
  int* flags = (int*)p; p += 64;
  float* als0 = (float*)p; p += (size_t)n * 4 * sizeof(float);
  float* ald0 = (float*)p; p += (size_t)n * 4 * sizeof(float);
  float* als1 = (float*)p; p += (size_t)n * sizeof(float);
  float* ald1 = (float*)p; p += (size_t)n * sizeof(float);
  int* cnt  = (int*)p; p += (size_t)n * sizeof(int);
  int* offb = (int*)p; p += (size_t)(n + 1) * sizeof(int) + 4;
  int* pos  = (int*)p; p += (size_t)n * sizeof(int);
  int* bsrc = (int*)p; p += (size_t)E * sizeof(int);

  detect_kernel<<<1, 256, 0, stream>>>(x, ei, flags);

  hipMemsetAsync(cnt, 0, (size_t)n * sizeof(int), stream);
  count_kernel<<<(E + 255) / 256, 256, 0, stream>>>(ei, E, n, flags, cnt);
  scan_kernel<<<1, 1024, 0, stream>>>(cnt, offb, pos, n);
  fill_kernel<<<(E + 255) / 256, 256, 0, stream>>>(ei, E, n, flags, pos, bsrc);

  int gm = (n + 127) / 128;
  // h = relu(x @ Wp + bp)
  mfma_gemm_kernel<1, true, true><<<dim3(gm, 4), 256, 0, stream>>>(x, Wp, bp, flags, h_buf, n, 256, 256);
  // xw0 = h @ W0
  mfma_gemm_kernel<0, false, false><<<dim3(gm, 4), 256, 0, stream>>>(h_buf, W0, nullptr, flags, xw_buf, n, 256, 256);
  al0_kernel<<<n, 256, 0, stream>>>(xw_buf, as0, ad0, flags, als0, ald0, n);
  // layer-0 aggregate + b0 + LN + residual + relu -> h1 (in-place rows of h_buf)
  agg_kernel<4, 64, true><<<n, 256, 0, stream>>>(xw_buf, als0, ald0, bsrc, offb, b0, g0, be0, flags, h_buf, h_buf, n);
  // xw1 = h1 @ W1
  mfma_gemm_kernel<0, false, false><<<dim3(gm, 2), 256, 0, stream>>>(h_buf, W1, nullptr, flags, xw_buf, n, 128, 256);
  al1_kernel<<<n, 128, 0, stream>>>(xw_buf, as1, ad1, flags, als1, ald1, n);
  // layer-1 aggregate + b1 + LN -> h2 (reuse h_buf as n x 128)
  agg_kernel<1, 128, false><<<n, 128, 0, stream>>>(xw_buf, als1, ald1, bsrc, offb, b1, g1, be1, flags, nullptr, h_buf, n);
  // pre-norm = h2 @ Wo + bo -> xw_buf
  mfma_gemm_kernel<0, false, true><<<dim3(gm, 2), 256, 0, stream>>>(h_buf, Wo, bo, flags, xw_buf, n, 128, 128);
  // out = row-normalize
  norm_kernel<<<n, 128, 0, stream>>>(xw_buf, outp, n);
}

// Round 5
// 880.276 us; speedup vs baseline: 1.3687x; 1.0663x over previous
//
#include <hip/hip_runtime.h>
#include <hip/hip_bf16.h>

typedef __bf16 bf16x8 __attribute__((ext_vector_type(8)));
typedef __bf16 bf16x4 __attribute__((ext_vector_type(4)));
typedef float f32x4 __attribute__((ext_vector_type(4)));

// ---------------- dtype-robust load helpers ----------------
__device__ __forceinline__ float getf(const void* p, size_t i, int isf32){
  return isf32 ? ((const float*)p)[i]
               : __bfloat162float(((const __hip_bfloat16*)p)[i]);
}
__device__ __forceinline__ int getedge(const void* p, long long idx, int is64, int n){
  long long v = is64 ? ((const long long*)p)[idx] : (long long)((const int*)p)[idx];
  v = v < 0 ? 0 : (v >= n ? (long long)(n - 1) : v);
  return (int)v;
}

__device__ __forceinline__ float bfly_sum(float v){
#pragma unroll
  for (int m = 32; m > 0; m >>= 1) v += __shfl_xor(v, m, 64);
  return v;
}
__device__ __forceinline__ float bfly_max(float v){
#pragma unroll
  for (int m = 32; m > 0; m >>= 1) v = fmaxf(v, __shfl_xor(v, m, 64));
  return v;
}

// ---------------- runtime dtype detection ----------------
__global__ __launch_bounds__(256) void detect_kernel(const void* x, const void* ei,
                                                     int* flags){
  __shared__ int cnt_sane, cnt_odd;
  int t = threadIdx.x;
  if (t == 0){ cnt_sane = 0; cnt_odd = 0; }
  __syncthreads();
  int sane = 0;
  for (int i = t; i < 4096; i += 256){
    float v = __bfloat162float(((const __hip_bfloat16*)x)[i]);
    if (fabsf(v) < 16.f) sane++;
  }
  atomicAdd(&cnt_sane, sane);
  int odd = 0;
  for (int i = t; i < 512; i += 256){
    if (((const int*)ei)[2 * i + 1] != 0) odd++;
  }
  atomicAdd(&cnt_odd, odd);
  __syncthreads();
  if (t == 0){
    flags[0] = (cnt_sane < 3900) ? 1 : 0;  // 1 => float inputs are fp32
    flags[1] = (cnt_odd == 0) ? 1 : 0;     // 1 => edge_index is int64
  }
}

// ---------------- graph bucketing ----------------
__global__ __launch_bounds__(256) void count_kernel(const void* __restrict__ ei, long long E,
                                                    int n, const int* __restrict__ flags,
                                                    int* __restrict__ cnt){
  int i = blockIdx.x * blockDim.x + threadIdx.x;
  if (i < E){
    int d = getedge(ei, E + i, flags[1], n);
    atomicAdd(&cnt[d], 1);
  }
}

__global__ __launch_bounds__(1024) void scan_kernel(const int* __restrict__ cnt, int* __restrict__ off,
                                                    int* __restrict__ pos, int n){
  __shared__ int wsum[16];
  __shared__ int carry_s;
  int tid = threadIdx.x, lane = tid & 63, wv = tid >> 6;
  if (tid == 0) carry_s = 0;
  __syncthreads();
  for (int base = 0; base < n; base += 1024){
    int i = base + tid;
    int v = (i < n) ? cnt[i] : 0;
    int s = v;
#pragma unroll
    for (int o = 1; o < 64; o <<= 1){ int t = __shfl_up(s, o, 64); if (lane >= o) s += t; }
    if (lane == 63) wsum[wv] = s;
    __syncthreads();
    int wo = 0;
    for (int w = 0; w < wv; w++) wo += wsum[w];
    int carry = carry_s;
    int excl = carry + wo + s - v;
    if (i < n){ off[i] = excl; pos[i] = excl; }
    __syncthreads();
    if (tid == 0){
      int tot = 0;
      for (int w = 0; w < 16; w++) tot += wsum[w];
      carry_s = carry + tot;
    }
    __syncthreads();
  }
  if (tid == 0) off[n] = carry_s;
}

__global__ __launch_bounds__(256) void fill_kernel(const void* __restrict__ ei, long long E,
                                                   int n, const int* __restrict__ flags,
                                                   int* __restrict__ pos, int* __restrict__ bsrc){
  int i = blockIdx.x * blockDim.x + threadIdx.x;
  if (i < E){
    int d = getedge(ei, E + i, flags[1], n);
    int s = getedge(ei, i, flags[1], n);
    int p = atomicAdd(&pos[d], 1);
    bsrc[p] = s;
  }
}

// ---------------- bf16 MFMA GEMM: C[M,N] = A[M,K] @ B[K,N] (+bias, relu) ----------------
// OMODE 0: C fp32, 1: C bf16.
template<int AMODE, int OMODE, bool RELU, bool BIAS>
__global__ __launch_bounds__(256) void mfma_gemm_kernel(const void* __restrict__ A,
    const void* __restrict__ B, const void* __restrict__ bias, const int* __restrict__ flags,
    void* __restrict__ C, int M, int N, int K)
{
  __shared__ __align__(16) __bf16 sA[128 * 40];
  __shared__ __align__(16) __bf16 sB[64 * 264];
  int f0 = flags[0];
  const bool af32 = (AMODE == 0) || (f0 != 0);
  int t = threadIdx.x;
  int bm = blockIdx.x * 128, bn = blockIdx.y * 64;

  for (int e = t; e < 64 * K; e += 256){
    int nn = e & 63, kk = e >> 6;
    sB[nn * 264 + kk] = (__bf16)getf(B, (size_t)kk * N + bn + nn, f0);
  }

  int wave = t >> 6, lane = t & 63, q = lane >> 4, mi = lane & 15;
  int m0w = (wave & 1) * 64, n0w = (wave >> 1) * 32;
  int k4 = (t & 7) * 4;
  int r0 = t >> 3;
  f32x4 acc[4][2] = {};
  __syncthreads();

  for (int k0 = 0; k0 < K; k0 += 32){
#pragma unroll
    for (int it = 0; it < 4; it++){
      int row = r0 + it * 32;
      int gr = bm + row;
      float vx = 0.f, vy = 0.f, vz = 0.f, vw = 0.f;
      if (gr < M){
        size_t g = (size_t)gr * K + k0 + k4;
        if (af32){
          const f32x4 v = *(const f32x4*)((const float*)A + g);
          vx = v.x; vy = v.y; vz = v.z; vw = v.w;
        } else {
          const __hip_bfloat16* bp8 = (const __hip_bfloat16*)A + g;
          vx = __bfloat162float(bp8[0]); vy = __bfloat162float(bp8[1]);
          vz = __bfloat162float(bp8[2]); vw = __bfloat162float(bp8[3]);
        }
      }
      bf16x4 pk;
      pk.x = (__bf16)vx; pk.y = (__bf16)vy; pk.z = (__bf16)vz; pk.w = (__bf16)vw;
      *(bf16x4*)&sA[row * 40 + k4] = pk;
    }
    __syncthreads();
    bf16x8 bfr0 = *(const bf16x8*)&sB[(n0w + 0 * 16 + mi) * 264 + k0 + q * 8];
    bf16x8 bfr1 = *(const bf16x8*)&sB[(n0w + 1 * 16 + mi) * 264 + k0 + q * 8];
#pragma unroll
    for (int mt = 0; mt < 4; mt++){
      bf16x8 afr = *(const bf16x8*)&sA[(m0w + mt * 16 + mi) * 40 + q * 8];
      acc[mt][0] = __builtin_amdgcn_mfma_f32_16x16x32_bf16(afr, bfr0, acc[mt][0], 0, 0, 0);
      acc[mt][1] = __builtin_amdgcn_mfma_f32_16x16x32_bf16(afr, bfr1, acc[mt][1], 0, 0, 0);
    }
    __syncthreads();
  }

#pragma unroll
  for (int mt = 0; mt < 4; mt++){
    int rowb = bm + m0w + mt * 16 + q * 4;
#pragma unroll
    for (int r = 0; r < 4; r++){
      int row = rowb + r;
      if (row < M){
#pragma unroll
        for (int nt = 0; nt < 2; nt++){
          int col = bn + n0w + nt * 16 + mi;
          float v = acc[mt][nt][r];
          if (BIAS) v += getf(bias, col, f0);
          if (RELU) v = fmaxf(v, 0.f);
          size_t idx = (size_t)row * N + col;
          if (OMODE == 0) ((float*)C)[idx] = v;
          else ((__hip_bfloat16*)C)[idx] = __float2bfloat16(v);
        }
      }
    }
  }
}

// ---------------- attention logits (xw is bf16 now) ----------------
__global__ __launch_bounds__(256) void al0_kernel(const __hip_bfloat16* __restrict__ xw,
    const void* __restrict__ a_s, const void* __restrict__ a_d, const int* __restrict__ flags,
    float* __restrict__ als, float* __restrict__ ald, int n)
{
  int f0 = flags[0];
  int i = blockIdx.x, t = threadIdx.x;
  int h = t >> 6, lane = t & 63;
  float v = __bfloat162float(xw[(size_t)i * 256 + t]);
  float ps = v * getf(a_s, t, f0);
  float pd = v * getf(a_d, t, f0);
  ps = bfly_sum(ps); pd = bfly_sum(pd);
  if (lane == 0){ als[(size_t)i * 4 + h] = ps; ald[(size_t)i * 4 + h] = pd; }
}

__global__ __launch_bounds__(128) void al1_kernel(const __hip_bfloat16* __restrict__ xw,
    const void* __restrict__ a_s, const void* __restrict__ a_d, const int* __restrict__ flags,
    float* __restrict__ als, float* __restrict__ ald, int n)
{
  __shared__ float rs[2], rd[2];
  int f0 = flags[0];
  int i = blockIdx.x, t = threadIdx.x;
  int wv = t >> 6, lane = t & 63;
  float v = __bfloat162float(xw[(size_t)i * 128 + t]);
  float ps = v * getf(a_s, t, f0);
  float pd = v * getf(a_d, t, f0);
  ps = bfly_sum(ps); pd = bfly_sum(pd);
  if (lane == 0){ rs[wv] = ps; rd[wv] = pd; }
  __syncthreads();
  if (t == 0){ als[i] = rs[0] + rs[1]; ald[i] = rd[0] + rd[1]; }
}

// ---------------- GAT aggregation (bf16 gather, 16B/lane) + bias + LN (+res+relu) ----------------
// Block = T threads. Each lane accumulates 8 channels (ch0 = (lane % LPR)*8); a wave
// covers EPW = 64/LPR edges per iteration; 8 edges per k-step across NW waves.
template<int H, int C, bool RES>
__global__ __launch_bounds__(H*C) void agg_kernel(
    const __hip_bfloat16* __restrict__ xw, const float* __restrict__ als, const float* __restrict__ ald,
    const int* __restrict__ bsrc, const int* __restrict__ off,
    const void* __restrict__ bias, const void* __restrict__ gamma,
    const void* __restrict__ beta, const int* __restrict__ flags,
    const float* __restrict__ res, float* __restrict__ outp, int n)
{
  constexpr int T = H * C;
  constexpr int NW = T / 64;        // waves per block
  constexpr int LPR = T / 8;        // lanes covering one row
  constexpr int EPW = 64 / LPR;     // edges per wave-iteration
  int f0 = flags[0];
  int i = blockIdx.x;
  int t = threadIdx.x, wv = t >> 6, lane = t & 63;
  int e0 = off[i];
  int deg = off[i + 1] - e0;
  int tot = deg + 1;                 // + self loop

  int sub = lane / LPR;              // which edge within wave group
  int rl  = lane % LPR;
  int ch0 = rl * 8;
  int head = ch0 / C;
  int pidx = wv * EPW + sub;         // 0..7 partial index

  __shared__ float s_w[H][68];
  __shared__ int   s_src[64];
  __shared__ float s_part[8][T + 8];
  __shared__ float s_red[NW];

  // per-head softmax stats (wave h handles head h)
  float m = -1e30f, linv = 0.f, ad_i = 0.f;
  if (wv < H){
    ad_i = ald[(size_t)i * H + wv];
    for (int j = lane; j < tot; j += 64){
      int s = (j < deg) ? bsrc[e0 + j] : i;
      float e = als[(size_t)s * H + wv] + ad_i;
      e = (e > 0.f) ? e : 0.2f * e;
      m = fmaxf(m, e);
    }
    m = bfly_max(m);
    float l = 0.f;
    for (int j = lane; j < tot; j += 64){
      int s = (j < deg) ? bsrc[e0 + j] : i;
      float e = als[(size_t)s * H + wv] + ad_i;
      e = (e > 0.f) ? e : 0.2f * e;
      l += __expf(e - m);
    }
    l = bfly_sum(l);
    linv = 1.f / l;
  }

  float macc[8] = {};
  for (int cb = 0; cb < tot; cb += 64){
    int cnt = min(64, tot - cb);
    __syncthreads();
    if (wv == 0){
      int j = cb + lane;
      s_src[lane] = (j < deg) ? bsrc[e0 + j] : i;
    }
    __syncthreads();
    if (wv < H){
      float wt = 0.f;
      if (lane < cnt){
        int s = s_src[lane];
        float e = als[(size_t)s * H + wv] + ad_i;
        e = (e > 0.f) ? e : 0.2f * e;
        wt = __expf(e - m) * linv;
      }
      s_w[wv][lane] = wt;
    }
    __syncthreads();
#pragma unroll
    for (int k = 0; k < 8; k++){
      if (k * 8 + wv * EPW >= cnt) break;        // wave-uniform
      int l = k * 8 + wv * EPW + sub;
      int row = s_src[l];
      float wt = s_w[head][l];
      const uint4 u = *(const uint4*)(xw + (size_t)row * T + ch0);
      macc[0] += wt * __uint_as_float(u.x << 16);
      macc[1] += wt * __uint_as_float(u.x & 0xffff0000u);
      macc[2] += wt * __uint_as_float(u.y << 16);
      macc[3] += wt * __uint_as_float(u.y & 0xffff0000u);
      macc[4] += wt * __uint_as_float(u.z << 16);
      macc[5] += wt * __uint_as_float(u.z & 0xffff0000u);
      macc[6] += wt * __uint_as_float(u.w << 16);
      macc[7] += wt * __uint_as_float(u.w & 0xffff0000u);
    }
  }
  __syncthreads();
  *(f32x4*)&s_part[pidx][ch0]     = (f32x4){macc[0], macc[1], macc[2], macc[3]};
  *(f32x4*)&s_part[pidx][ch0 + 4] = (f32x4){macc[4], macc[5], macc[6], macc[7]};
  __syncthreads();

  float v = getf(bias, t, f0);
#pragma unroll
  for (int p2 = 0; p2 < 8; p2++) v += s_part[p2][t];

  // LayerNorm over the row (== block)
  float s1 = bfly_sum(v);
  if (lane == 0) s_red[wv] = s1;
  __syncthreads();
  float mu = 0.f;
#pragma unroll
  for (int w = 0; w < NW; w++) mu += s_red[w];
  mu *= (1.f / T);
  __syncthreads();
  float d = v - mu;
  float s2 = bfly_sum(d * d);
  if (lane == 0) s_red[wv] = s2;
  __syncthreads();
  float var = 0.f;
#pragma unroll
  for (int w = 0; w < NW; w++) var += s_red[w];
  var *= (1.f / T);
  float y = d * rsqrtf(var + 1e-5f) * getf(gamma, t, f0) + getf(beta, t, f0);
  if constexpr (RES){
    y = y + res[(size_t)i * T + t];
    y = fmaxf(y, 0.f);
  }
  outp[(size_t)i * T + t] = y;
}

// ---------------- row L2-normalize ----------------
__global__ __launch_bounds__(128) void norm_kernel(const float* __restrict__ in,
                                                   float* __restrict__ outp, int n)
{
  __shared__ float sred[2];
  int i = blockIdx.x, t = threadIdx.x, wv = t >> 6, lane = t & 63;
  float v = in[(size_t)i * 128 + t];
  float ss = bfly_sum(v * v);
  if (lane == 0) sred[wv] = ss;
  __syncthreads();
  float inv = 1.f / fmaxf(sqrtf(sred[0] + sred[1]), 1e-12f);
  outp[(size_t)i * 128 + t] = v * inv;
}

// ---------------- launch ----------------
extern "C" void kernel_launch(void* const* d_in, const int* in_sizes, int n_in,
                              void* d_out, int out_size, void* d_ws, size_t ws_size,
                              hipStream_t stream)
{
  const void* x   = d_in[0];
  const void* ei  = d_in[1];
  const void* Wp  = d_in[2];
  const void* bp  = d_in[3];
  const void* W0  = d_in[4];
  const void* as0 = d_in[5];
  const void* ad0 = d_in[6];
  const void* b0  = d_in[7];
  const void* W1  = d_in[8];
  const void* as1 = d_in[9];
  const void* ad1 = d_in[10];
  const void* b1  = d_in[11];
  const void* g0  = d_in[12];
  const void* be0 = d_in[13];
  const void* g1  = d_in[14];
  const void* be1 = d_in[15];
  const void* Wo  = d_in[16];
  const void* bo  = d_in[17];
  float* outp = (float*)d_out;

  const int n = in_sizes[0] / 256;   // 50000
  const int E = in_sizes[1] / 2;     // 800000

  char* w = (char*)d_ws;
  size_t SZ = (size_t)n * 256 * sizeof(float);
  float* h_buf  = (float*)w;                         // h -> h1 -> h2 (fp32)
  char*  xw_reg = w + SZ;                            // bf16 gather tables / fp32 prenorm
  __hip_bfloat16* xw_bf = (__hip_bfloat16*)xw_reg;
  float* prenorm = (float*)xw_reg;
  char* p = w + 2 * SZ;
  int* flags = (int*)p; p += 64;
  float* als0 = (float*)p; p += (size_t)n * 4 * sizeof(float);
  float* ald0 = (float*)p; p += (size_t)n * 4 * sizeof(float);
  float* als1 = (float*)p; p += (size_t)n * sizeof(float);
  float* ald1 = (float*)p; p += (size_t)n * sizeof(float);
  int* cnt  = (int*)p; p += (size_t)n * sizeof(int);
  int* offb = (int*)p; p += (size_t)(n + 1) * sizeof(int) + 4;
  int* pos  = (int*)p; p += (size_t)n * sizeof(int);
  int* bsrc = (int*)p; p += (size_t)E * sizeof(int);

  detect_kernel<<<1, 256, 0, stream>>>(x, ei, flags);

  hipMemsetAsync(cnt, 0, (size_t)n * sizeof(int), stream);
  count_kernel<<<(E + 255) / 256, 256, 0, stream>>>(ei, E, n, flags, cnt);
  scan_kernel<<<1, 1024, 0, stream>>>(cnt, offb, pos, n);
  fill_kernel<<<(E + 255) / 256, 256, 0, stream>>>(ei, E, n, flags, pos, bsrc);

  int gm = (n + 127) / 128;
  // h = relu(x @ Wp + bp)  (fp32 out)
  mfma_gemm_kernel<1, 0, true, true><<<dim3(gm, 4), 256, 0, stream>>>(x, Wp, bp, flags, h_buf, n, 256, 256);
  // xw0 = h @ W0  (bf16 out)
  mfma_gemm_kernel<0, 1, false, false><<<dim3(gm, 4), 256, 0, stream>>>(h_buf, W0, nullptr, flags, xw_bf, n, 256, 256);
  al0_kernel<<<n, 256, 0, stream>>>(xw_bf, as0, ad0, flags, als0, ald0, n);
  // layer-0 aggregate + b0 + LN + residual + relu -> h1 (in-place rows of h_buf)
  agg_kernel<4, 64, true><<<n, 256, 0, stream>>>(xw_bf, als0, ald0, bsrc, offb, b0, g0, be0, flags, h_buf, h_buf, n);
  // xw1 = h1 @ W1  (bf16 out)
  mfma_gemm_kernel<0, 1, false, false><<<dim3(gm, 2), 256, 0, stream>>>(h_buf, W1, nullptr, flags, xw_bf, n, 128, 256);
  al1_kernel<<<n, 128, 0, stream>>>(xw_bf, as1, ad1, flags, als1, ald1, n);
  // layer-1 aggregate + b1 + LN -> h2 (reuse h_buf as n x 128 fp32)
  agg_kernel<1, 128, false><<<n, 128, 0, stream>>>(xw_bf, als1, ald1, bsrc, offb, b1, g1, be1, flags, nullptr, h_buf, n);
  // pre-norm = h2 @ Wo + bo (fp32 out; overwrites xw region which is no longer needed)
  mfma_gemm_kernel<0, 0, false, true><<<dim3(gm, 2), 256, 0, stream>>>(h_buf, Wo, bo, flags, prenorm, n, 128, 128);
  // out = row-normalize
  norm_kernel<<<n, 128, 0, stream>>>(prenorm, outp, n);
}